// Round 1
// baseline (1933.633 us; speedup 1.0000x reference)
//
#include <hip/hip_runtime.h>
#include <math.h>

#define V 64
#define T 8192
#define DA 256
#define DS 256
#define KR 8
#define KA 40
#define KRDU 512

// ---- output layout (floats, concatenated in reference return order) ----
#define OUT_PDET   0
#define OUT_TAU    1
#define OUT_YHAT   2
#define OUT_E      42
#define OUT_EVIEW  524330
#define OUT_RVIEW  524394
#define OUT_IVIEW  524458
#define OUT_STARTS 524522
#define OUT_ENDS   1048810
#define OUT_FLAG   1573098

// ---- workspace layout (floats) ----
#define WS_W    0     // 256: w = Wwin^T zs_n
#define WS_ESUM 256   // 64: per-view sum of e (atomic)

#define HPAD 260      // 32 h-rows, stride 260 floats (1040 B: 16B-aligned, banks 0/8/16/24 across row quads)
#define WPAD 68       // W tile rows stride 68 floats (272 B: 16B-aligned)

// ============================ kernel A: small heads ============================
__global__ __launch_bounds__(256) void head_kernel(
    const float* __restrict__ alpha, const float* __restrict__ pi,
    const float* __restrict__ US, const float* __restrict__ Ws_w,
    const float* __restrict__ Ws_b, const float* __restrict__ det_w,
    const float* __restrict__ det_b, const float* __restrict__ cls_w,
    const float* __restrict__ cls_b, const float* __restrict__ Wwin,
    const float* __restrict__ tau_c0, const float* __restrict__ lamU,
    const float* __restrict__ lamC, const float* __restrict__ lamP,
    const float* __restrict__ lamPi, const float* __restrict__ nu,
    const float* __restrict__ risk,
    float* __restrict__ out, float* __restrict__ ws)
{
    __shared__ float us[KRDU];
    __shared__ float zs[DS];
    __shared__ float zsn[DS];
    __shared__ float red[256];
    const int tid = threadIdx.x;

    us[tid]       = US[tid];
    us[tid + 256] = US[tid + 256];
    __syncthreads();

    // zs = US @ Ws_w^T + Ws_b
    float acc = Ws_b[tid];
    const float4* wrow = (const float4*)(Ws_w + (size_t)tid * KRDU);
    #pragma unroll 4
    for (int j = 0; j < KRDU / 4; ++j) {
        float4 w4 = wrow[j];
        acc += w4.x * us[4*j] + w4.y * us[4*j+1] + w4.z * us[4*j+2] + w4.w * us[4*j+3];
    }
    zs[tid] = acc;

    // s = zs . det_w + det_b
    red[tid] = acc * det_w[tid];
    __syncthreads();
    for (int off = 128; off > 0; off >>= 1) { if (tid < off) red[tid] += red[tid+off]; __syncthreads(); }
    float s_det = red[0] + det_b[0];
    __syncthreads();

    // ||zs||
    red[tid] = acc * acc;
    __syncthreads();
    for (int off = 128; off > 0; off >>= 1) { if (tid < off) red[tid] += red[tid+off]; __syncthreads(); }
    float inv_n = 1.0f / fmaxf(sqrtf(red[0]), 1e-12f);
    __syncthreads();
    zsn[tid] = acc * inv_n;

    // entropy(alpha)
    float term = 0.0f;
    if (tid < V) { float a = alpha[tid]; term = -a * logf(a + 1e-8f); }
    red[tid] = term;
    __syncthreads();
    for (int off = 128; off > 0; off >>= 1) { if (tid < off) red[tid] += red[tid+off]; __syncthreads(); }
    float C_alpha = 1.0f - red[0] / logf((float)V);
    __syncthreads();

    // entropy(pi)
    term = 0.0f;
    if (tid < KR) { float p = pi[tid]; term = -p * logf(p + 1e-8f); }
    red[tid] = term;
    __syncthreads();
    for (int off = 128; off > 0; off >>= 1) { if (tid < off) red[tid] += red[tid+off]; __syncthreads(); }
    float u_pi = red[0] / logf((float)KR);
    __syncthreads();

    float tau = tau_c0[0] - lamU[0]*nu[0] - lamC[0]*C_alpha + lamP[0]*risk[0] + lamPi[0]*u_pi;
    if (tid == 0) {
        out[OUT_TAU]  = tau;
        out[OUT_PDET] = 1.0f / (1.0f + expf(-(s_det - tau)));
    }

    // y_hat = sigmoid(zs @ cls_w^T + cls_b)
    if (tid < KA) {
        float a2 = cls_b[tid];
        const float* cr = cls_w + (size_t)tid * DS;
        for (int i = 0; i < DS; ++i) a2 += zs[i] * cr[i];
        out[OUT_YHAT + tid] = 1.0f / (1.0f + expf(-a2));
    }

    // w[d] = sum_s Wwin[s,d] * zsn[s]   (coalesced over d = tid)
    float wd = 0.0f;
    for (int s = 0; s < DS; ++s) wd += Wwin[(size_t)s * DA + tid] * zsn[s];
    ws[WS_W + tid] = wd;

    if (tid < V) {
        out[OUT_RVIEW + tid] = -0.5f * alpha[tid];
        ws[WS_ESUM + tid] = 0.0f;   // zero accumulators for kernel B
    }
}

// ============================ kernel B: e scores ============================
// block = 256 threads, 32 rows (one v per block: 8192 % 32 == 0).
// thread (rg = tid>>4, sg = tid&15): rows rg*2+{0,1}, s = sc*64 + sg*4+{0..3}
#define FMA8(hv0, hv1, wq) \
    a00 += (hv0)*(wq).x; a01 += (hv0)*(wq).y; a02 += (hv0)*(wq).z; a03 += (hv0)*(wq).w; \
    a10 += (hv1)*(wq).x; a11 += (hv1)*(wq).y; a12 += (hv1)*(wq).z; a13 += (hv1)*(wq).w;

__global__ __launch_bounds__(256) void escore_kernel(
    const float* __restrict__ h, const float* __restrict__ Wwin,
    float* __restrict__ ws, float* __restrict__ out)
{
    __shared__ float hs[32 * HPAD];   // 33280 B
    __shared__ float Wt[64 * WPAD];   // 17408 B
    __shared__ float wv_s[DA];
    __shared__ float ered[32];

    const int tid  = threadIdx.x;
    const int row0 = blockIdx.x * 32;

    // stage 32 h rows (coalesced float4, 16B-aligned LDS stores)
    const float4* hg = (const float4*)(h + (size_t)row0 * DA);
    #pragma unroll
    for (int i = 0; i < 8; ++i) {
        int q = tid + 256 * i;
        int r = q >> 6, c = q & 63;
        float4 v4 = hg[q];
        *(float4*)&hs[r * HPAD + c * 4] = v4;
    }
    wv_s[tid] = ws[WS_W + tid];

    const int sg = tid & 15;
    const int rg = tid >> 4;
    const int r0 = rg * 2;

    float nrm2_0 = 0.0f, nrm2_1 = 0.0f;

    for (int sc = 0; sc < 4; ++sc) {
        float a00=0,a01=0,a02=0,a03=0,a10=0,a11=0,a12=0,a13=0;
        for (int dc = 0; dc < 4; ++dc) {
            __syncthreads();
            // load 64s x 64d W tile, transposed into Wt[d][s]
            #pragma unroll
            for (int i = 0; i < 4; ++i) {
                int q = tid + 256 * i;          // 0..1023
                int sl = q >> 4, dq = q & 15;
                float4 w4 = *(const float4*)(Wwin + (size_t)(sc*64 + sl) * DA + dc*64 + dq*4);
                Wt[(dq*4+0) * WPAD + sl] = w4.x;
                Wt[(dq*4+1) * WPAD + sl] = w4.y;
                Wt[(dq*4+2) * WPAD + sl] = w4.z;
                Wt[(dq*4+3) * WPAD + sl] = w4.w;
            }
            __syncthreads();
            const float* hp0 = &hs[ r0      * HPAD + dc*64];
            const float* hp1 = &hs[(r0 + 1) * HPAD + dc*64];
            #pragma unroll
            for (int d4 = 0; d4 < 64; d4 += 4) {
                float4 h0 = *(const float4*)(hp0 + d4);
                float4 h1 = *(const float4*)(hp1 + d4);
                float4 w0 = *(const float4*)&Wt[(d4+0)*WPAD + sg*4];
                float4 w1 = *(const float4*)&Wt[(d4+1)*WPAD + sg*4];
                float4 w2 = *(const float4*)&Wt[(d4+2)*WPAD + sg*4];
                float4 w3 = *(const float4*)&Wt[(d4+3)*WPAD + sg*4];
                FMA8(h0.x, h1.x, w0);
                FMA8(h0.y, h1.y, w1);
                FMA8(h0.z, h1.z, w2);
                FMA8(h0.w, h1.w, w3);
            }
        }
        nrm2_0 += a00*a00 + a01*a01 + a02*a02 + a03*a03;
        nrm2_1 += a10*a10 + a11*a11 + a12*a12 + a13*a13;
    }

    // numerator: h . w (partial over d = sg::16)
    float num0 = 0.0f, num1 = 0.0f;
    for (int d = sg; d < DA; d += 16) {
        float wv = wv_s[d];
        num0 += hs[ r0      * HPAD + d] * wv;
        num1 += hs[(r0 + 1) * HPAD + d] * wv;
    }
    // reduce over the 16 sg lanes (contiguous within the wave)
    for (int m = 8; m >= 1; m >>= 1) {
        num0   += __shfl_xor(num0, m);
        num1   += __shfl_xor(num1, m);
        nrm2_0 += __shfl_xor(nrm2_0, m);
        nrm2_1 += __shfl_xor(nrm2_1, m);
    }
    if (sg == 0) {
        float e0 = num0 / fmaxf(sqrtf(nrm2_0), 1e-12f);
        float e1 = num1 / fmaxf(sqrtf(nrm2_1), 1e-12f);
        out[OUT_E + row0 + r0]     = e0;
        out[OUT_E + row0 + r0 + 1] = e1;
        ered[r0]     = e0;
        ered[r0 + 1] = e1;
    }
    __syncthreads();
    if (tid == 0) {
        float s = 0.0f;
        #pragma unroll
        for (int i = 0; i < 32; ++i) s += ered[i];
        atomicAdd(&ws[WS_ESUM + (row0 >> 13)], s);
    }
}

// ============================ kernel C1: view-level finalize ============================
__global__ void finalize_kernel(const float* __restrict__ alpha,
                                const float* __restrict__ ws,
                                float* __restrict__ out)
{
    int v = threadIdx.x;   // 64 threads = 1 wave
    float E = ws[WS_ESUM + v] * (1.0f / 8192.0f);
    out[OUT_EVIEW + v] = E;
    float r = -0.5f * alpha[v];
    bool Iv = (E >= r);
    out[OUT_IVIEW + v] = Iv ? 1.0f : 0.0f;
    unsigned long long bal = __ballot(Iv);
    if (v == 0) {
        float p = out[OUT_PDET];
        out[OUT_FLAG] = ((p >= 0.5f) && (bal == 0ULL)) ? 1.0f : 0.0f;
    }
}

// ============================ kernel C2: starts/ends ============================
__global__ __launch_bounds__(256) void intervals_kernel(
    const float* __restrict__ alpha, float* __restrict__ out)
{
    int idx = blockIdx.x * 256 + threadIdx.x;   // exactly V*T threads
    int v = idx >> 13;
    int t = idx & (T - 1);
    const float* e = out + OUT_E;
    float r = -0.5f * alpha[v];
    bool Ii = (e[idx] >= r);
    bool Ip = (t > 0)     && (e[idx - 1] >= r);
    bool In = (t < T - 1) && (e[idx + 1] >= r);
    out[OUT_STARTS + idx] = (Ii && !Ip) ? 1.0f : 0.0f;
    out[OUT_ENDS   + idx] = (Ii && !In) ? 1.0f : 0.0f;
}

// ============================ launcher ============================
extern "C" void kernel_launch(void* const* d_in, const int* in_sizes, int n_in,
                              void* d_out, int out_size, void* d_ws, size_t ws_size,
                              hipStream_t stream)
{
    const float* h      = (const float*)d_in[0];
    const float* alpha  = (const float*)d_in[1];
    const float* pi     = (const float*)d_in[2];
    const float* US     = (const float*)d_in[3];
    // d_in[4], d_in[5] (Wc_w, Wc_b) are dead code in the reference
    const float* Ws_w   = (const float*)d_in[6];
    const float* Ws_b   = (const float*)d_in[7];
    const float* det_w  = (const float*)d_in[8];
    const float* det_b  = (const float*)d_in[9];
    const float* cls_w  = (const float*)d_in[10];
    const float* cls_b  = (const float*)d_in[11];
    const float* Wwin   = (const float*)d_in[12];
    const float* tau_c0 = (const float*)d_in[13];
    const float* lamU   = (const float*)d_in[14];
    const float* lamC   = (const float*)d_in[15];
    const float* lamP   = (const float*)d_in[16];
    const float* lamPi  = (const float*)d_in[17];
    const float* nu     = (const float*)d_in[18];
    const float* risk   = (const float*)d_in[19];
    float* out = (float*)d_out;
    float* ws  = (float*)d_ws;

    head_kernel<<<1, 256, 0, stream>>>(alpha, pi, US, Ws_w, Ws_b, det_w, det_b,
                                       cls_w, cls_b, Wwin, tau_c0, lamU, lamC,
                                       lamP, lamPi, nu, risk, out, ws);
    escore_kernel<<<(V * T) / 32, 256, 0, stream>>>(h, Wwin, ws, out);
    finalize_kernel<<<1, 64, 0, stream>>>(alpha, ws, out);
    intervals_kernel<<<(V * T) / 256, 256, 0, stream>>>(alpha, out);
}

// Round 2
// 1225.905 us; speedup vs baseline: 1.5773x; 1.5773x over previous
//
#include <hip/hip_runtime.h>
#include <math.h>

#define V 64
#define T 8192
#define DA 256
#define DS 256
#define KR 8
#define KA 40
#define KRDU 512

// ---- output layout (floats, concatenated in reference return order) ----
#define OUT_PDET   0
#define OUT_TAU    1
#define OUT_YHAT   2
#define OUT_E      42
#define OUT_EVIEW  524330
#define OUT_RVIEW  524394
#define OUT_IVIEW  524458
#define OUT_STARTS 524522
#define OUT_ENDS   1048810
#define OUT_FLAG   1573098

// ---- workspace layout (floats) ----
#define WS_W    0     // 256: w = Wwin^T zs_n  (atomic-accumulated by wvec_kernel)
#define WS_ESUM 256   // 64: per-view sum of e
#define WS_ZSN  320   // 256: normalized zs

typedef __attribute__((ext_vector_type(8))) short short8;
typedef __attribute__((ext_vector_type(4))) float f32x4;

// fp32 -> bf16 round-to-nearest-even (values are well-behaved, no NaN path)
__device__ __forceinline__ unsigned pack_bf16(float a, float b) {
    union { float f; unsigned u; } x, y; x.f = a; y.f = b;
    unsigned ua = (x.u + 0x7FFFu + ((x.u >> 16) & 1u)) >> 16;
    unsigned ub = (y.u + 0x7FFFu + ((y.u >> 16) & 1u)) & 0xFFFF0000u;
    return ua | ub;
}

// ============================ kernel A: small heads ============================
__global__ __launch_bounds__(256) void head_kernel(
    const float* __restrict__ alpha, const float* __restrict__ pi,
    const float* __restrict__ US, const float* __restrict__ Ws_w,
    const float* __restrict__ Ws_b, const float* __restrict__ det_w,
    const float* __restrict__ det_b, const float* __restrict__ cls_w,
    const float* __restrict__ cls_b,
    const float* __restrict__ tau_c0, const float* __restrict__ lamU,
    const float* __restrict__ lamC, const float* __restrict__ lamP,
    const float* __restrict__ lamPi, const float* __restrict__ nu,
    const float* __restrict__ risk,
    float* __restrict__ out, float* __restrict__ ws)
{
    __shared__ float us[KRDU];
    __shared__ float zs[DS];
    __shared__ float red[256];
    const int tid = threadIdx.x;
    const int rr = tid >> 4;     // 0..15
    const int c  = tid & 15;

    us[tid]       = US[tid];
    us[tid + 256] = US[tid + 256];
    __syncthreads();

    // zs = US @ Ws_w^T  (coalesced: 16 rows per pass, 16 lanes per row)
    for (int rg = 0; rg < 16; ++rg) {
        int row = rg * 16 + rr;
        const float4* wr = (const float4*)(Ws_w + (size_t)row * KRDU);
        float a = 0.0f;
        #pragma unroll
        for (int jj = 0; jj < 8; ++jj) {
            float4 w4 = wr[jj * 16 + c];
            int j0 = (jj * 16 + c) * 4;
            a += w4.x * us[j0] + w4.y * us[j0+1] + w4.z * us[j0+2] + w4.w * us[j0+3];
        }
        #pragma unroll
        for (int m = 8; m >= 1; m >>= 1) a += __shfl_xor(a, m);
        if (c == 0) zs[row] = a;
    }
    __syncthreads();
    float zv = zs[tid] + Ws_b[tid];
    __syncthreads();
    zs[tid] = zv;

    // s = zs . det_w + det_b
    red[tid] = zv * det_w[tid];
    __syncthreads();
    for (int off = 128; off > 0; off >>= 1) { if (tid < off) red[tid] += red[tid+off]; __syncthreads(); }
    float s_det = red[0] + det_b[0];
    __syncthreads();

    // ||zs||
    red[tid] = zv * zv;
    __syncthreads();
    for (int off = 128; off > 0; off >>= 1) { if (tid < off) red[tid] += red[tid+off]; __syncthreads(); }
    float inv_n = 1.0f / fmaxf(sqrtf(red[0]), 1e-12f);
    __syncthreads();
    ws[WS_ZSN + tid] = zv * inv_n;

    // entropy(alpha)
    float term = 0.0f;
    if (tid < V) { float a = alpha[tid]; term = -a * logf(a + 1e-8f); }
    red[tid] = term;
    __syncthreads();
    for (int off = 128; off > 0; off >>= 1) { if (tid < off) red[tid] += red[tid+off]; __syncthreads(); }
    float C_alpha = 1.0f - red[0] / logf((float)V);
    __syncthreads();

    // entropy(pi)
    term = 0.0f;
    if (tid < KR) { float p = pi[tid]; term = -p * logf(p + 1e-8f); }
    red[tid] = term;
    __syncthreads();
    for (int off = 128; off > 0; off >>= 1) { if (tid < off) red[tid] += red[tid+off]; __syncthreads(); }
    float u_pi = red[0] / logf((float)KR);
    __syncthreads();

    float tau = tau_c0[0] - lamU[0]*nu[0] - lamC[0]*C_alpha + lamP[0]*risk[0] + lamPi[0]*u_pi;
    if (tid == 0) {
        out[OUT_TAU]  = tau;
        out[OUT_PDET] = 1.0f / (1.0f + expf(-(s_det - tau)));
    }

    // y_hat = sigmoid(zs @ cls_w^T + cls_b)   (coalesced, 3 row-groups cover 40 rows)
    for (int rg = 0; rg < 3; ++rg) {
        int row = rg * 16 + rr;
        float a = 0.0f;
        if (row < KA) {
            const float4* cr4 = (const float4*)(cls_w + (size_t)row * DS);
            #pragma unroll
            for (int jj = 0; jj < 4; ++jj) {
                float4 w4 = cr4[jj * 16 + c];
                int j0 = (jj * 16 + c) * 4;
                a += w4.x * zs[j0] + w4.y * zs[j0+1] + w4.z * zs[j0+2] + w4.w * zs[j0+3];
            }
        }
        #pragma unroll
        for (int m = 8; m >= 1; m >>= 1) a += __shfl_xor(a, m);
        if (c == 0 && row < KA) out[OUT_YHAT + row] = 1.0f / (1.0f + expf(-(a + cls_b[row])));
    }

    // zero accumulators for wvec/escore
    ws[WS_W + tid] = 0.0f;
    if (tid < V) {
        out[OUT_RVIEW + tid] = -0.5f * alpha[tid];
        ws[WS_ESUM + tid] = 0.0f;
    }
}

// ============================ kernel A2: w = Wwin^T zsn ============================
__global__ __launch_bounds__(256) void wvec_kernel(const float* __restrict__ Wwin,
                                                   float* __restrict__ ws)
{
    __shared__ float zl[16];
    const int b = blockIdx.x;      // 16 blocks, 16 s-rows each
    const int tid = threadIdx.x;   // d
    if (tid < 16) zl[tid] = ws[WS_ZSN + b * 16 + tid];
    __syncthreads();
    float a = 0.0f;
    #pragma unroll
    for (int s = 0; s < 16; ++s) a += Wwin[(size_t)(b * 16 + s) * DA + tid] * zl[s];
    atomicAdd(&ws[WS_W + tid], a);
}

// ============================ kernel B: e scores (bf16 MFMA norms) ============================
// 512 blocks x 256 threads; block = 1024 contiguous rows (one v), 64 tiles of 16 rows.
// Wave w holds B-fragments for s in [w*64, w*64+64) in registers (128 VGPRs).
#define HROWB 264   // bf16 row stride in LDS (528 B = 33*16: 16B-aligned, phase-minimal banks)

__global__ __launch_bounds__(256, 2) void escore_kernel(
    const float* __restrict__ h, const float* __restrict__ Wwin,
    float* __restrict__ ws, float* __restrict__ out)
{
    __shared__ unsigned short hsb[2][16 * HROWB];   // 16896 B
    __shared__ float numbuf[2][16];
    __shared__ float nrmbuf[2][4][16];

    const int tid  = threadIdx.x;
    const int lane = tid & 63;
    const int wv   = tid >> 6;      // wave 0..3
    const int ln15 = lane & 15;
    const int lq   = lane >> 4;     // 0..3

    // ---- prologue: wave's W fragments, fp32 -> bf16 ----
    short8 Wf[4][8];
    {
        const int nbase = wv * 64 + ln15;
        #pragma unroll
        for (int st = 0; st < 4; ++st) {
            const float* wrow = Wwin + (size_t)(nbase + st * 16) * DA + lq * 8;
            #pragma unroll
            for (int kk = 0; kk < 8; ++kk) {
                float4 f0 = *(const float4*)(wrow + kk * 32);
                float4 f1 = *(const float4*)(wrow + kk * 32 + 4);
                union { short8 s; unsigned u[4]; } pk;
                pk.u[0] = pack_bf16(f0.x, f0.y);
                pk.u[1] = pack_bf16(f0.z, f0.w);
                pk.u[2] = pack_bf16(f1.x, f1.y);
                pk.u[3] = pack_bf16(f1.z, f1.w);
                Wf[st][kk] = pk.s;
            }
        }
    }
    const float4 wq = *(const float4*)(ws + WS_W + 4 * lane);   // w[4*lane .. +3]

    const long rowbase0 = (long)blockIdx.x * 1024;
    float esum = 0.0f;

    for (int tile = 0; tile < 64; ++tile) {
        const int p = tile & 1;
        const long rowbase = rowbase0 + tile * 16;

        // stage: coalesced global fp32 loads; fp32 num partials; bf16 LDS staging
        const float4* hg = (const float4*)(h + rowbase * DA);
        float4 f[4];
        #pragma unroll
        for (int i = 0; i < 4; ++i) f[i] = hg[tid + 256 * i];   // row = wv+4i, col4 = lane

        #pragma unroll
        for (int i = 0; i < 4; ++i) {
            float np = f[i].x * wq.x + f[i].y * wq.y + f[i].z * wq.z + f[i].w * wq.w;
            #pragma unroll
            for (int m = 32; m >= 1; m >>= 1) np += __shfl_xor(np, m);
            if (lane == 0) numbuf[p][wv + 4 * i] = np;
        }
        #pragma unroll
        for (int i = 0; i < 4; ++i) {
            unsigned u0 = pack_bf16(f[i].x, f[i].y);
            unsigned u1 = pack_bf16(f[i].z, f[i].w);
            *(uint2*)&hsb[p][(wv + 4 * i) * HROWB + lane * 4] = make_uint2(u0, u1);
        }
        __syncthreads();   // hs[p], numbuf[p] ready

        // MFMA: z-tiles, accumulate row norms
        f32x4 acc[4];
        #pragma unroll
        for (int st = 0; st < 4; ++st) acc[st] = (f32x4){0.f, 0.f, 0.f, 0.f};
        #pragma unroll
        for (int kk = 0; kk < 8; ++kk) {
            short8 af = *(const short8*)&hsb[p][ln15 * HROWB + kk * 32 + lq * 8];
            acc[0] = __builtin_amdgcn_mfma_f32_16x16x32_bf16(af, Wf[0][kk], acc[0], 0, 0, 0);
            acc[1] = __builtin_amdgcn_mfma_f32_16x16x32_bf16(af, Wf[1][kk], acc[1], 0, 0, 0);
            acc[2] = __builtin_amdgcn_mfma_f32_16x16x32_bf16(af, Wf[2][kk], acc[2], 0, 0, 0);
            acc[3] = __builtin_amdgcn_mfma_f32_16x16x32_bf16(af, Wf[3][kk], acc[3], 0, 0, 0);
        }
        float nr2[4];
        #pragma unroll
        for (int reg = 0; reg < 4; ++reg)
            nr2[reg] = acc[0][reg]*acc[0][reg] + acc[1][reg]*acc[1][reg]
                     + acc[2][reg]*acc[2][reg] + acc[3][reg]*acc[3][reg];
        #pragma unroll
        for (int m = 1; m <= 8; m <<= 1) {
            nr2[0] += __shfl_xor(nr2[0], m);
            nr2[1] += __shfl_xor(nr2[1], m);
            nr2[2] += __shfl_xor(nr2[2], m);
            nr2[3] += __shfl_xor(nr2[3], m);
        }
        if (ln15 == 0) {
            #pragma unroll
            for (int reg = 0; reg < 4; ++reg) nrmbuf[p][wv][lq * 4 + reg] = nr2[reg];
        }
        __syncthreads();   // nrmbuf[p] ready

        if (tid < 16) {
            float nn = nrmbuf[p][0][tid] + nrmbuf[p][1][tid] + nrmbuf[p][2][tid] + nrmbuf[p][3][tid];
            float e = numbuf[p][tid] / fmaxf(sqrtf(nn), 1e-12f);
            out[OUT_E + rowbase + tid] = e;
            esum += e;
        }
    }

    // block e-sum -> per-view accumulator
    if (tid < 64) {
        float s = (tid < 16) ? esum : 0.0f;
        #pragma unroll
        for (int m = 1; m <= 8; m <<= 1) s += __shfl_xor(s, m);
        if (tid == 0) atomicAdd(&ws[WS_ESUM + (blockIdx.x >> 3)], s);
    }
}

// ============================ kernel B2: exact-fp32 fixup near decision boundary ============================
__global__ __launch_bounds__(256) void fixup_kernel(
    const float* __restrict__ h, const float* __restrict__ Wwin,
    const float* __restrict__ alpha, const float* __restrict__ ws,
    float* __restrict__ out)
{
    const int tid  = threadIdx.x;
    const int lane = tid & 63;
    const long row = (long)blockIdx.x * 256 + tid;
    const float e  = out[OUT_E + row];
    const float r  = -0.5f * alpha[row >> 13];
    bool flag = fabsf(e - r) < 2e-3f;
    unsigned long long mask = __ballot(flag);
    while (mask) {
        int t = __ffsll((unsigned long long)mask) - 1;
        mask &= mask - 1;
        const long frow = (long)blockIdx.x * 256 + (tid & ~63) + t;
        const float* hr = h + frow * DA;
        float z0 = 0.f, z1 = 0.f, z2 = 0.f, z3 = 0.f;
        const float* wp = Wwin + (size_t)(lane * 4) * DA;
        for (int d = 0; d < DA; ++d) {
            float hd = hr[d];
            z0 += hd * wp[d];
            z1 += hd * wp[d + DA];
            z2 += hd * wp[d + 2 * DA];
            z3 += hd * wp[d + 3 * DA];
        }
        float nrm = z0*z0 + z1*z1 + z2*z2 + z3*z3;
        float num = 0.f;
        #pragma unroll
        for (int j = 0; j < 4; ++j) num += hr[lane + 64 * j] * ws[WS_W + lane + 64 * j];
        #pragma unroll
        for (int m = 32; m >= 1; m >>= 1) { nrm += __shfl_xor(nrm, m); num += __shfl_xor(num, m); }
        if (lane == 0) out[OUT_E + frow] = num / fmaxf(sqrtf(nrm), 1e-12f);
    }
}

// ============================ kernel C1: view-level finalize ============================
__global__ void finalize_kernel(const float* __restrict__ alpha,
                                const float* __restrict__ ws,
                                float* __restrict__ out)
{
    int v = threadIdx.x;   // 64 threads = 1 wave
    float E = ws[WS_ESUM + v] * (1.0f / 8192.0f);
    out[OUT_EVIEW + v] = E;
    float r = -0.5f * alpha[v];
    bool Iv = (E >= r);
    out[OUT_IVIEW + v] = Iv ? 1.0f : 0.0f;
    unsigned long long bal = __ballot(Iv);
    if (v == 0) {
        float p = out[OUT_PDET];
        out[OUT_FLAG] = ((p >= 0.5f) && (bal == 0ULL)) ? 1.0f : 0.0f;
    }
}

// ============================ kernel C2: starts/ends ============================
__global__ __launch_bounds__(256) void intervals_kernel(
    const float* __restrict__ alpha, float* __restrict__ out)
{
    int idx = blockIdx.x * 256 + threadIdx.x;   // exactly V*T threads
    int v = idx >> 13;
    int t = idx & (T - 1);
    const float* e = out + OUT_E;
    float r = -0.5f * alpha[v];
    bool Ii = (e[idx] >= r);
    bool Ip = (t > 0)     && (e[idx - 1] >= r);
    bool In = (t < T - 1) && (e[idx + 1] >= r);
    out[OUT_STARTS + idx] = (Ii && !Ip) ? 1.0f : 0.0f;
    out[OUT_ENDS   + idx] = (Ii && !In) ? 1.0f : 0.0f;
}

// ============================ launcher ============================
extern "C" void kernel_launch(void* const* d_in, const int* in_sizes, int n_in,
                              void* d_out, int out_size, void* d_ws, size_t ws_size,
                              hipStream_t stream)
{
    const float* h      = (const float*)d_in[0];
    const float* alpha  = (const float*)d_in[1];
    const float* pi     = (const float*)d_in[2];
    const float* US     = (const float*)d_in[3];
    // d_in[4], d_in[5] (Wc_w, Wc_b) dead code
    const float* Ws_w   = (const float*)d_in[6];
    const float* Ws_b   = (const float*)d_in[7];
    const float* det_w  = (const float*)d_in[8];
    const float* det_b  = (const float*)d_in[9];
    const float* cls_w  = (const float*)d_in[10];
    const float* cls_b  = (const float*)d_in[11];
    const float* Wwin   = (const float*)d_in[12];
    const float* tau_c0 = (const float*)d_in[13];
    const float* lamU   = (const float*)d_in[14];
    const float* lamC   = (const float*)d_in[15];
    const float* lamP   = (const float*)d_in[16];
    const float* lamPi  = (const float*)d_in[17];
    const float* nu     = (const float*)d_in[18];
    const float* risk   = (const float*)d_in[19];
    float* out = (float*)d_out;
    float* ws  = (float*)d_ws;

    head_kernel<<<1, 256, 0, stream>>>(alpha, pi, US, Ws_w, Ws_b, det_w, det_b,
                                       cls_w, cls_b, tau_c0, lamU, lamC,
                                       lamP, lamPi, nu, risk, out, ws);
    wvec_kernel<<<16, 256, 0, stream>>>(Wwin, ws);
    escore_kernel<<<512, 256, 0, stream>>>(h, Wwin, ws, out);
    fixup_kernel<<<(V * T) / 256, 256, 0, stream>>>(h, Wwin, alpha, ws, out);
    finalize_kernel<<<1, 64, 0, stream>>>(alpha, ws, out);
    intervals_kernel<<<(V * T) / 256, 256, 0, stream>>>(alpha, out);
}

// Round 3
// 1023.256 us; speedup vs baseline: 1.8897x; 1.1980x over previous
//
#include <hip/hip_runtime.h>
#include <math.h>

#define V 64
#define T 8192
#define DA 256
#define DS 256
#define KR 8
#define KA 40
#define KRDU 512

// ---- output layout (floats, concatenated in reference return order) ----
#define OUT_PDET   0
#define OUT_TAU    1
#define OUT_YHAT   2
#define OUT_E      42
#define OUT_EVIEW  524330
#define OUT_RVIEW  524394
#define OUT_IVIEW  524458
#define OUT_STARTS 524522
#define OUT_ENDS   1048810
#define OUT_FLAG   1573098

// ---- workspace layout ----
#define WS_W    0      // float[256]: w = Wwin^T zsn (atomic-accumulated)
#define WS_ESUM 256    // float[64]: per-view sum of e
#define WS_ZSN  320    // float[256]: normalized zs
#define WS_CNT  576    // int: worklist counter
#define WS_LIST 640    // int[CAP]: flagged row indices

#define CAP    65536
#define MARGIN 4e-3f
#define HROWB  264     // bf16 row stride in LDS (528 B)

typedef __attribute__((ext_vector_type(8))) short short8;
typedef __attribute__((ext_vector_type(4))) float f32x4;

__device__ __forceinline__ unsigned pack_bf16(float a, float b) {
    union { float f; unsigned u; } x, y; x.f = a; y.f = b;
    unsigned ua = (x.u + 0x7FFFu + ((x.u >> 16) & 1u)) >> 16;
    unsigned ub = (y.u + 0x7FFFu + ((y.u >> 16) & 1u)) & 0xFFFF0000u;
    return ua | ub;
}

// ============================ kernel A: small heads ============================
__global__ __launch_bounds__(256) void head_kernel(
    const float* __restrict__ alpha, const float* __restrict__ pi,
    const float* __restrict__ US, const float* __restrict__ Ws_w,
    const float* __restrict__ Ws_b, const float* __restrict__ det_w,
    const float* __restrict__ det_b, const float* __restrict__ cls_w,
    const float* __restrict__ cls_b,
    const float* __restrict__ tau_c0, const float* __restrict__ lamU,
    const float* __restrict__ lamC, const float* __restrict__ lamP,
    const float* __restrict__ lamPi, const float* __restrict__ nu,
    const float* __restrict__ risk,
    float* __restrict__ out, float* __restrict__ ws, int* __restrict__ wsi)
{
    __shared__ float us[KRDU];
    __shared__ float zs[DS];
    __shared__ float red[256];
    const int tid = threadIdx.x;
    const int rr = tid >> 4;
    const int c  = tid & 15;

    us[tid]       = US[tid];
    us[tid + 256] = US[tid + 256];
    __syncthreads();

    // zs = US @ Ws_w^T (coalesced)
    for (int rg = 0; rg < 16; ++rg) {
        int row = rg * 16 + rr;
        const float4* wr = (const float4*)(Ws_w + (size_t)row * KRDU);
        float a = 0.0f;
        #pragma unroll
        for (int jj = 0; jj < 8; ++jj) {
            float4 w4 = wr[jj * 16 + c];
            int j0 = (jj * 16 + c) * 4;
            a += w4.x * us[j0] + w4.y * us[j0+1] + w4.z * us[j0+2] + w4.w * us[j0+3];
        }
        #pragma unroll
        for (int m = 8; m >= 1; m >>= 1) a += __shfl_xor(a, m);
        if (c == 0) zs[row] = a;
    }
    __syncthreads();
    float zv = zs[tid] + Ws_b[tid];
    __syncthreads();
    zs[tid] = zv;

    // s = zs . det_w + det_b
    red[tid] = zv * det_w[tid];
    __syncthreads();
    for (int off = 128; off > 0; off >>= 1) { if (tid < off) red[tid] += red[tid+off]; __syncthreads(); }
    float s_det = red[0] + det_b[0];
    __syncthreads();

    // ||zs||
    red[tid] = zv * zv;
    __syncthreads();
    for (int off = 128; off > 0; off >>= 1) { if (tid < off) red[tid] += red[tid+off]; __syncthreads(); }
    float inv_n = 1.0f / fmaxf(sqrtf(red[0]), 1e-12f);
    __syncthreads();
    ws[WS_ZSN + tid] = zv * inv_n;

    // entropy(alpha)
    float term = 0.0f;
    if (tid < V) { float a = alpha[tid]; term = -a * logf(a + 1e-8f); }
    red[tid] = term;
    __syncthreads();
    for (int off = 128; off > 0; off >>= 1) { if (tid < off) red[tid] += red[tid+off]; __syncthreads(); }
    float C_alpha = 1.0f - red[0] / logf((float)V);
    __syncthreads();

    // entropy(pi)
    term = 0.0f;
    if (tid < KR) { float p = pi[tid]; term = -p * logf(p + 1e-8f); }
    red[tid] = term;
    __syncthreads();
    for (int off = 128; off > 0; off >>= 1) { if (tid < off) red[tid] += red[tid+off]; __syncthreads(); }
    float u_pi = red[0] / logf((float)KR);
    __syncthreads();

    float tau = tau_c0[0] - lamU[0]*nu[0] - lamC[0]*C_alpha + lamP[0]*risk[0] + lamPi[0]*u_pi;
    if (tid == 0) {
        out[OUT_TAU]  = tau;
        out[OUT_PDET] = 1.0f / (1.0f + expf(-(s_det - tau)));
        wsi[WS_CNT]   = 0;
    }

    // y_hat
    for (int rg = 0; rg < 3; ++rg) {
        int row = rg * 16 + rr;
        float a = 0.0f;
        if (row < KA) {
            const float4* cr4 = (const float4*)(cls_w + (size_t)row * DS);
            #pragma unroll
            for (int jj = 0; jj < 4; ++jj) {
                float4 w4 = cr4[jj * 16 + c];
                int j0 = (jj * 16 + c) * 4;
                a += w4.x * zs[j0] + w4.y * zs[j0+1] + w4.z * zs[j0+2] + w4.w * zs[j0+3];
            }
        }
        #pragma unroll
        for (int m = 8; m >= 1; m >>= 1) a += __shfl_xor(a, m);
        if (c == 0 && row < KA) out[OUT_YHAT + row] = 1.0f / (1.0f + expf(-(a + cls_b[row])));
    }

    ws[WS_W + tid] = 0.0f;
    if (tid < V) {
        out[OUT_RVIEW + tid] = -0.5f * alpha[tid];
        ws[WS_ESUM + tid] = 0.0f;
    }
}

// ============================ kernel A2: w = Wwin^T zsn ============================
__global__ __launch_bounds__(256) void wvec_kernel(const float* __restrict__ Wwin,
                                                   float* __restrict__ ws)
{
    __shared__ float zl[16];
    const int b = blockIdx.x;
    const int tid = threadIdx.x;
    if (tid < 16) zl[tid] = ws[WS_ZSN + b * 16 + tid];
    __syncthreads();
    float a = 0.0f;
    #pragma unroll
    for (int s = 0; s < 16; ++s) a += Wwin[(size_t)(b * 16 + s) * DA + tid] * zl[s];
    atomicAdd(&ws[WS_W + tid], a);
}

// ============================ kernel B: e scores ============================
// 512 blocks x 256 threads; block = 1024 rows of one view, 64 tiles of 16 rows.
// Wave w: B-frags for s in [w*64,(w+1)*64). num computed from MFMA z via zsn.
// Per-wave PRIVATE partial arrays in LDS -> one barrier per tile (staging) only.
__global__ __launch_bounds__(256, 2) void escore_kernel(
    const float* __restrict__ h, const float* __restrict__ Wwin,
    const float* __restrict__ alpha,
    float* __restrict__ ws, int* __restrict__ wsi, float* __restrict__ out)
{
    __shared__ unsigned short hsb[2][16 * HROWB];   // 16896 B
    __shared__ float part_n[4][1024];               // 16 KB
    __shared__ float part_u[4][1024];               // 16 KB
    __shared__ float red[4];

    const int tid  = threadIdx.x;
    const int lane = tid & 63;
    const int wv   = tid >> 6;
    const int ln15 = lane & 15;
    const int lq   = lane >> 4;

    // ---- prologue: W fragments (fp32 -> bf16), s = wv*64 + st*16 + ln15 ----
    short8 Wf[4][8];
    {
        const int nbase = wv * 64 + ln15;
        #pragma unroll
        for (int st = 0; st < 4; ++st) {
            const float* wrow = Wwin + (size_t)(nbase + st * 16) * DA + lq * 8;
            #pragma unroll
            for (int kk = 0; kk < 8; ++kk) {
                float4 f0 = *(const float4*)(wrow + kk * 32);
                float4 f1 = *(const float4*)(wrow + kk * 32 + 4);
                union { short8 s; unsigned u[4]; } pk;
                pk.u[0] = pack_bf16(f0.x, f0.y);
                pk.u[1] = pack_bf16(f0.z, f0.w);
                pk.u[2] = pack_bf16(f1.x, f1.y);
                pk.u[3] = pack_bf16(f1.z, f1.w);
                Wf[st][kk] = pk.s;
            }
        }
    }
    float zl[4];
    #pragma unroll
    for (int st = 0; st < 4; ++st) zl[st] = ws[WS_ZSN + wv * 64 + st * 16 + ln15];

    const int view = blockIdx.x >> 3;
    const float rv = -0.5f * alpha[view];
    const long rowbase0 = (long)blockIdx.x * 1024;

    // preload tile 0 (row = wv+4i, col4 = lane)
    float4 f[4];
    {
        const float4* hg = (const float4*)(h + rowbase0 * DA);
        #pragma unroll
        for (int i = 0; i < 4; ++i) f[i] = hg[tid + 256 * i];
    }

    for (int tile = 0; tile < 64; ++tile) {
        const int p = tile & 1;

        // stage current tile to LDS (bf16)
        #pragma unroll
        for (int i = 0; i < 4; ++i) {
            unsigned u0 = pack_bf16(f[i].x, f[i].y);
            unsigned u1 = pack_bf16(f[i].z, f[i].w);
            *(uint2*)&hsb[p][(wv + 4 * i) * HROWB + lane * 4] = make_uint2(u0, u1);
        }
        __syncthreads();

        // prefetch next tile (issues now, consumed next iteration)
        {
            int nt = (tile < 63) ? tile + 1 : 63;
            const float4* ng = (const float4*)(h + (rowbase0 + (long)nt * 16) * DA);
            #pragma unroll
            for (int i = 0; i < 4; ++i) f[i] = ng[tid + 256 * i];
        }

        // MFMA z-tile: rows m = lq*4+reg, cols s = wv*64+st*16+ln15
        f32x4 acc[4];
        #pragma unroll
        for (int st = 0; st < 4; ++st) acc[st] = (f32x4){0.f, 0.f, 0.f, 0.f};
        #pragma unroll
        for (int kk = 0; kk < 8; ++kk) {
            short8 af = *(const short8*)&hsb[p][ln15 * HROWB + kk * 32 + lq * 8];
            acc[0] = __builtin_amdgcn_mfma_f32_16x16x32_bf16(af, Wf[0][kk], acc[0], 0, 0, 0);
            acc[1] = __builtin_amdgcn_mfma_f32_16x16x32_bf16(af, Wf[1][kk], acc[1], 0, 0, 0);
            acc[2] = __builtin_amdgcn_mfma_f32_16x16x32_bf16(af, Wf[2][kk], acc[2], 0, 0, 0);
            acc[3] = __builtin_amdgcn_mfma_f32_16x16x32_bf16(af, Wf[3][kk], acc[3], 0, 0, 0);
        }

        // per-row partials over this wave's 64 s: nrm and num
        float nr[4], nu[4];
        #pragma unroll
        for (int reg = 0; reg < 4; ++reg) {
            nr[reg] = acc[0][reg]*acc[0][reg] + acc[1][reg]*acc[1][reg]
                    + acc[2][reg]*acc[2][reg] + acc[3][reg]*acc[3][reg];
            nu[reg] = acc[0][reg]*zl[0] + acc[1][reg]*zl[1]
                    + acc[2][reg]*zl[2] + acc[3][reg]*zl[3];
        }
        #pragma unroll
        for (int m = 1; m <= 8; m <<= 1) {
            #pragma unroll
            for (int reg = 0; reg < 4; ++reg) {
                nr[reg] += __shfl_xor(nr[reg], m);
                nu[reg] += __shfl_xor(nu[reg], m);
            }
        }
        if (ln15 == 0) {
            *(float4*)&part_n[wv][tile * 16 + lq * 4] = make_float4(nr[0], nr[1], nr[2], nr[3]);
            *(float4*)&part_u[wv][tile * 16 + lq * 4] = make_float4(nu[0], nu[1], nu[2], nu[3]);
        }
        // no barrier here: part arrays are wave-private
    }
    __syncthreads();

    // finalize: 1024 rows, 4 per thread
    float esum = 0.0f;
    #pragma unroll
    for (int j = 0; j < 4; ++j) {
        int r = j * 256 + tid;
        float nn = part_n[0][r] + part_n[1][r] + part_n[2][r] + part_n[3][r];
        float uu = part_u[0][r] + part_u[1][r] + part_u[2][r] + part_u[3][r];
        float e = uu / fmaxf(sqrtf(nn), 1e-12f);
        out[OUT_E + rowbase0 + r] = e;
        esum += e;
        if (fabsf(e - rv) < MARGIN) {
            int idx = atomicAdd(&wsi[WS_CNT], 1);
            if (idx < CAP) wsi[WS_LIST + idx] = (int)(rowbase0 + r);
        }
    }
    #pragma unroll
    for (int m = 1; m <= 32; m <<= 1) esum += __shfl_xor(esum, m);
    if (lane == 0) red[wv] = esum;
    __syncthreads();
    if (tid == 0) atomicAdd(&ws[WS_ESUM + view], red[0] + red[1] + red[2] + red[3]);
}

// ============================ kernel B2: exact-fp32 fixup (worklist) ============================
__global__ __launch_bounds__(256) void fixup_kernel(
    const float* __restrict__ h, const float* __restrict__ Wwin,
    const float* __restrict__ alpha, const float* __restrict__ ws,
    const int* __restrict__ wsi, float* __restrict__ out)
{
    __shared__ float hrow[DA];
    __shared__ float red[8];
    const int tid  = threadIdx.x;
    const int lane = tid & 63;
    const int wv   = tid >> 6;
    const int cnt  = wsi[WS_CNT];
    const int m    = cnt < CAP ? cnt : CAP;

    for (int i = blockIdx.x; i < m; i += gridDim.x) {
        const int row = wsi[WS_LIST + i];
        hrow[tid] = h[(size_t)row * DA + tid];
        __syncthreads();
        const float4* wr = (const float4*)(Wwin + (size_t)tid * DA);
        const float4* h4 = (const float4*)hrow;
        float z0 = 0.f, z1 = 0.f, z2 = 0.f, z3 = 0.f;
        #pragma unroll 4
        for (int j = 0; j < 64; j += 4) {
            float4 a, b;
            a = wr[j];   b = h4[j];   z0 += a.x*b.x + a.y*b.y + a.z*b.z + a.w*b.w;
            a = wr[j+1]; b = h4[j+1]; z1 += a.x*b.x + a.y*b.y + a.z*b.z + a.w*b.w;
            a = wr[j+2]; b = h4[j+2]; z2 += a.x*b.x + a.y*b.y + a.z*b.z + a.w*b.w;
            a = wr[j+3]; b = h4[j+3]; z3 += a.x*b.x + a.y*b.y + a.z*b.z + a.w*b.w;
        }
        float zz  = (z0 + z1) + (z2 + z3);
        float nrm = zz * zz;
        float num = hrow[tid] * ws[WS_W + tid];
        #pragma unroll
        for (int s = 1; s <= 32; s <<= 1) { nrm += __shfl_xor(nrm, s); num += __shfl_xor(num, s); }
        if (lane == 0) { red[wv] = nrm; red[4 + wv] = num; }
        __syncthreads();
        if (tid == 0) {
            float nn = red[0] + red[1] + red[2] + red[3];
            float uu = red[4] + red[5] + red[6] + red[7];
            out[OUT_E + row] = uu / fmaxf(sqrtf(nn), 1e-12f);
        }
        __syncthreads();
    }

    // overflow fallback (cnt > CAP never happens in practice; kept for strict correctness)
    if (cnt > CAP) {
        for (long i = blockIdx.x; i < (long)V * T; i += gridDim.x) {
            float r = -0.5f * alpha[i >> 13];
            if (fabsf(out[OUT_E + i] - r) >= MARGIN) continue;
            hrow[tid] = h[(size_t)i * DA + tid];
            __syncthreads();
            const float4* wr = (const float4*)(Wwin + (size_t)tid * DA);
            const float4* h4 = (const float4*)hrow;
            float z0 = 0.f, z1 = 0.f, z2 = 0.f, z3 = 0.f;
            for (int j = 0; j < 64; j += 4) {
                float4 a, b;
                a = wr[j];   b = h4[j];   z0 += a.x*b.x + a.y*b.y + a.z*b.z + a.w*b.w;
                a = wr[j+1]; b = h4[j+1]; z1 += a.x*b.x + a.y*b.y + a.z*b.z + a.w*b.w;
                a = wr[j+2]; b = h4[j+2]; z2 += a.x*b.x + a.y*b.y + a.z*b.z + a.w*b.w;
                a = wr[j+3]; b = h4[j+3]; z3 += a.x*b.x + a.y*b.y + a.z*b.z + a.w*b.w;
            }
            float zz  = (z0 + z1) + (z2 + z3);
            float nrm = zz * zz;
            float num = hrow[tid] * ws[WS_W + tid];
            for (int s = 1; s <= 32; s <<= 1) { nrm += __shfl_xor(nrm, s); num += __shfl_xor(num, s); }
            if (lane == 0) { red[wv] = nrm; red[4 + wv] = num; }
            __syncthreads();
            if (tid == 0) {
                float nn = red[0] + red[1] + red[2] + red[3];
                float uu = red[4] + red[5] + red[6] + red[7];
                out[OUT_E + i] = uu / fmaxf(sqrtf(nn), 1e-12f);
            }
            __syncthreads();
        }
    }
}

// ============================ kernel C1: view-level finalize ============================
__global__ void finalize_kernel(const float* __restrict__ alpha,
                                const float* __restrict__ ws,
                                float* __restrict__ out)
{
    int v = threadIdx.x;
    float E = ws[WS_ESUM + v] * (1.0f / 8192.0f);
    out[OUT_EVIEW + v] = E;
    float r = -0.5f * alpha[v];
    bool Iv = (E >= r);
    out[OUT_IVIEW + v] = Iv ? 1.0f : 0.0f;
    unsigned long long bal = __ballot(Iv);
    if (v == 0) {
        float p = out[OUT_PDET];
        out[OUT_FLAG] = ((p >= 0.5f) && (bal == 0ULL)) ? 1.0f : 0.0f;
    }
}

// ============================ kernel C2: starts/ends ============================
__global__ __launch_bounds__(256) void intervals_kernel(
    const float* __restrict__ alpha, float* __restrict__ out)
{
    int idx = blockIdx.x * 256 + threadIdx.x;
    int v = idx >> 13;
    int t = idx & (T - 1);
    const float* e = out + OUT_E;
    float r = -0.5f * alpha[v];
    bool Ii = (e[idx] >= r);
    bool Ip = (t > 0)     && (e[idx - 1] >= r);
    bool In = (t < T - 1) && (e[idx + 1] >= r);
    out[OUT_STARTS + idx] = (Ii && !Ip) ? 1.0f : 0.0f;
    out[OUT_ENDS   + idx] = (Ii && !In) ? 1.0f : 0.0f;
}

// ============================ launcher ============================
extern "C" void kernel_launch(void* const* d_in, const int* in_sizes, int n_in,
                              void* d_out, int out_size, void* d_ws, size_t ws_size,
                              hipStream_t stream)
{
    const float* h      = (const float*)d_in[0];
    const float* alpha  = (const float*)d_in[1];
    const float* pi     = (const float*)d_in[2];
    const float* US     = (const float*)d_in[3];
    const float* Ws_w   = (const float*)d_in[6];
    const float* Ws_b   = (const float*)d_in[7];
    const float* det_w  = (const float*)d_in[8];
    const float* det_b  = (const float*)d_in[9];
    const float* cls_w  = (const float*)d_in[10];
    const float* cls_b  = (const float*)d_in[11];
    const float* Wwin   = (const float*)d_in[12];
    const float* tau_c0 = (const float*)d_in[13];
    const float* lamU   = (const float*)d_in[14];
    const float* lamC   = (const float*)d_in[15];
    const float* lamP   = (const float*)d_in[16];
    const float* lamPi  = (const float*)d_in[17];
    const float* nu     = (const float*)d_in[18];
    const float* risk   = (const float*)d_in[19];
    float* out = (float*)d_out;
    float* ws  = (float*)d_ws;
    int*   wsi = (int*)d_ws;

    head_kernel<<<1, 256, 0, stream>>>(alpha, pi, US, Ws_w, Ws_b, det_w, det_b,
                                       cls_w, cls_b, tau_c0, lamU, lamC,
                                       lamP, lamPi, nu, risk, out, ws, wsi);
    wvec_kernel<<<16, 256, 0, stream>>>(Wwin, ws);
    escore_kernel<<<512, 256, 0, stream>>>(h, Wwin, alpha, ws, wsi, out);
    fixup_kernel<<<512, 256, 0, stream>>>(h, Wwin, alpha, ws, wsi, out);
    finalize_kernel<<<1, 64, 0, stream>>>(alpha, ws, out);
    intervals_kernel<<<(V * T) / 256, 256, 0, stream>>>(alpha, out);
}